// Round 11
// baseline (160.840 us; speedup 1.0000x reference)
//
#include <hip/hip_runtime.h>
#include <math.h>

#define B_N 524288
#define C_N 40
constexpr int BLOCK  = 320;   // 5 waves; 320*4 = 1280 floats = 32 rows of C=40
constexpr int VEC    = 4;
constexpr int UNROLL = 4;     // 4 float4-pairs; tile = 5120 floats (== 0 mod 40)
constexpr int GRID   = 4096;  // ONE tile per block: 4096*5120 == B_N*C_N exactly
constexpr int NREP   = 32;    // accumulator replicas to spread atomic contention

typedef float f32x4 __attribute__((ext_vector_type(4)));

// Nontemporal streaming load (bypass L1 allocation) — R9's proven win.
__device__ __forceinline__ f32x4 ldnt(const float* p) {
    return __builtin_nontemporal_load(reinterpret_cast<const f32x4*>(p));
}

// Churn kernel: each block processes exactly one tile then retires. Deep
// memory pipelining comes from the command processor refilling CUs with
// fresh blocks (the D2D-copy mechanism), not from per-wave ILP.
__global__ __launch_bounds__(BLOCK) void bdl_accum(
    const float* __restrict__ pred, const float* __restrict__ tgt,
    float* __restrict__ gacc)
{
    constexpr float LN9 = 2.1972245773362196f;
    constexpr int   W   = BLOCK * VEC;                       // 1280

    const int tid = threadIdx.x;
    const size_t base = (size_t)blockIdx.x * (W * UNROLL) + (size_t)tid * VEC;

    f32x4 p[UNROLL], t[UNROLL];
    #pragma unroll
    for (int u = 0; u < UNROLL; ++u) {
        p[u] = ldnt(pred + base + (size_t)u * W);
        t[u] = ldnt(tgt  + base + (size_t)u * W);
    }

    float cntp[VEC] = {0.f,0.f,0.f,0.f};
    float sall[VEC] = {0.f,0.f,0.f,0.f};
    float spos[VEC] = {0.f,0.f,0.f,0.f};
    float spe[VEC]  = {0.f,0.f,0.f,0.f};
    float sne[VEC]  = {0.f,0.f,0.f,0.f};

    #pragma unroll
    for (int u = 0; u < UNROLL; ++u) {
        #pragma unroll
        for (int j = 0; j < VEC; ++j) {
            const float x  = p[u][j];
            const float tv = t[u][j];
            const float e  = __expf(-fabsf(x));
            const float sp_ = __logf(1.f + e);            // softplus(-|x|)
            const float bce = sp_ + fmaxf(x, 0.f) - x * tv;
            const float bpos = (x >  LN9) ? bce : 0.f;    // easy positive
            const float bneg = (x < -LN9) ? bce : 0.f;    // easy negative
            cntp[j] += tv;
            sall[j] += bce;
            spos[j]  = fmaf(tv, bce,   spos[j]);
            spe[j]   = fmaf(tv, bpos,  spe[j]);           // t * easy-pos
            sne[j]   = fmaf(-tv, bneg, sne[j] + bneg);    // (1-t) * easy-neg
        }
    }

    __shared__ float lacc[C_N * 5];
    if (tid < C_N * 5) lacc[tid] = 0.f;
    __syncthreads();
    const int c0 = (tid * VEC) % C_N;          // constant classes per thread
    #pragma unroll
    for (int j = 0; j < VEC; ++j) {
        float* a = &lacc[(c0 + j) * 5];
        atomicAdd(a + 0, cntp[j]);
        atomicAdd(a + 1, sall[j]);
        atomicAdd(a + 2, spos[j]);
        atomicAdd(a + 3, spe[j]);
        atomicAdd(a + 4, sne[j]);
    }
    __syncthreads();
    if (tid < C_N * 5)
        atomicAdd(&gacc[(blockIdx.x % NREP) * (C_N * 5) + tid], lacc[tid]);
}

__global__ void bdl_final(const float* __restrict__ gacc, float* __restrict__ out)
{
    __shared__ float acc[C_N * 5];
    const int tid = threadIdx.x;
    if (tid < C_N * 5) {
        float s = 0.f;
        #pragma unroll
        for (int r = 0; r < NREP; ++r) s += gacc[r * (C_N * 5) + tid];
        acc[tid] = s;
    }
    __syncthreads();
    if (tid == 0) {
        const float Bf  = (float)B_N;
        const float bal = 0.5f * Bf;               // PROP * batch
        float tot = 0.f;
        for (int c = 0; c < C_N; ++c) {
            const float cntp = acc[c * 5 + 0];
            const float sall = acc[c * 5 + 1];
            const float sp   = acc[c * 5 + 2];
            const float spe  = acc[c * 5 + 3];
            const float sne  = acc[c * 5 + 4];
            const float sn   = sall - sp;
            const bool posmaj = (cntp >= bal);     // pos_gt; else neg_gt
            const float nmaj = posmaj ? cntp : (Bf - cntp);
            const float nmin = Bf - nmaj;
            const float smaj = posmaj ? (sp - spe) : (sn - sne);
            const float smin = posmaj ? sn : sp;
            const float wmaj = bal / fmaxf(nmaj, 1.f);
            const float wmin = (nmin > 0.f) ? ((Bf - bal) / fmaxf(nmin, 1.f)) : 1.f;
            tot += smaj * wmaj + smin * wmin;
        }
        out[0] = tot / (Bf * (float)C_N);
    }
}

extern "C" void kernel_launch(void* const* d_in, const int* in_sizes, int n_in,
                              void* d_out, int out_size, void* d_ws, size_t ws_size,
                              hipStream_t stream) {
    const float* pred = (const float*)d_in[0];
    const float* tgt  = (const float*)d_in[1];
    float* gacc = (float*)d_ws;                       // NREP*200 floats = 25.6 KB
    hipMemsetAsync(gacc, 0, NREP * C_N * 5 * sizeof(float), stream);
    bdl_accum<<<GRID, BLOCK, 0, stream>>>(pred, tgt, gacc);
    bdl_final<<<1, 256, 0, stream>>>(gacc, (float*)d_out);
}

// Round 12
// 79.486 us; speedup vs baseline: 2.0235x; 2.0235x over previous
//
#include <hip/hip_runtime.h>
#include <math.h>

#define B_N 524288
#define C_N 40
constexpr int BLOCK  = 640;   // 10 waves/block
constexpr int VEC    = 4;
constexpr int UNROLL = 2;     // tile = 640*4*2 = 5120 floats (== 0 mod 40)
constexpr int GRID   = 768;   // 3 blocks/CU exactly = 30/32 waves, single round
constexpr int NREP   = 32;    // accumulator replicas to spread atomic contention

typedef float f32x4 __attribute__((ext_vector_type(4)));

// Nontemporal streaming load (bypass L1 allocation) — R9's proven win.
__device__ __forceinline__ f32x4 ldnt(const float* p) {
    return __builtin_nontemporal_load(reinterpret_cast<const f32x4*>(p));
}

// R9 body at 1.5x the resident waves/CU (20 -> 30). nt removes the L1
// allocation thrash that made high-TLP lose pre-nt (R5).
__global__ __launch_bounds__(BLOCK) void bdl_accum(
    const float* __restrict__ pred, const float* __restrict__ tgt,
    float* __restrict__ gacc)
{
    constexpr float  LN9    = 2.1972245773362196f;
    constexpr int    W      = BLOCK * VEC;                   // 2560 (== 0 mod 40)
    constexpr size_t TILE   = (size_t)W * UNROLL;            // 5120
    constexpr size_t STRIDE = (size_t)GRID * TILE;
    constexpr size_t TOTAL  = (size_t)B_N * C_N;

    float cntp[VEC] = {0.f,0.f,0.f,0.f};
    float sall[VEC] = {0.f,0.f,0.f,0.f};
    float spos[VEC] = {0.f,0.f,0.f,0.f};
    float spe[VEC]  = {0.f,0.f,0.f,0.f};
    float sne[VEC]  = {0.f,0.f,0.f,0.f};

    const int tid = threadIdx.x;

    for (size_t base = (size_t)blockIdx.x * TILE + (size_t)tid * VEC;
         base < TOTAL; base += STRIDE) {
        f32x4 p[UNROLL], t[UNROLL];
        #pragma unroll
        for (int u = 0; u < UNROLL; ++u) {
            p[u] = ldnt(pred + base + (size_t)u * W);
            t[u] = ldnt(tgt  + base + (size_t)u * W);
        }
        #pragma unroll
        for (int u = 0; u < UNROLL; ++u) {
            #pragma unroll
            for (int j = 0; j < VEC; ++j) {
                const float x  = p[u][j];
                const float tv = t[u][j];
                const float e  = __expf(-fabsf(x));
                const float sp_ = __logf(1.f + e);            // softplus(-|x|)
                const float bce = sp_ + fmaxf(x, 0.f) - x * tv;
                const float bpos = (x >  LN9) ? bce : 0.f;    // easy positive
                const float bneg = (x < -LN9) ? bce : 0.f;    // easy negative
                cntp[j] += tv;
                sall[j] += bce;
                spos[j]  = fmaf(tv, bce,   spos[j]);
                spe[j]   = fmaf(tv, bpos,  spe[j]);           // t * easy-pos
                sne[j]   = fmaf(-tv, bneg, sne[j] + bneg);    // (1-t) * easy-neg
            }
        }
    }

    __shared__ float lacc[C_N * 5];
    if (tid < C_N * 5) lacc[tid] = 0.f;
    __syncthreads();
    const int c0 = (tid * VEC) % C_N;          // constant classes per thread
    #pragma unroll
    for (int j = 0; j < VEC; ++j) {
        float* a = &lacc[(c0 + j) * 5];
        atomicAdd(a + 0, cntp[j]);
        atomicAdd(a + 1, sall[j]);
        atomicAdd(a + 2, spos[j]);
        atomicAdd(a + 3, spe[j]);
        atomicAdd(a + 4, sne[j]);
    }
    __syncthreads();
    if (tid < C_N * 5)
        atomicAdd(&gacc[(blockIdx.x % NREP) * (C_N * 5) + tid], lacc[tid]);
}

__global__ void bdl_final(const float* __restrict__ gacc, float* __restrict__ out)
{
    __shared__ float acc[C_N * 5];
    const int tid = threadIdx.x;
    if (tid < C_N * 5) {
        float s = 0.f;
        #pragma unroll
        for (int r = 0; r < NREP; ++r) s += gacc[r * (C_N * 5) + tid];
        acc[tid] = s;
    }
    __syncthreads();
    if (tid == 0) {
        const float Bf  = (float)B_N;
        const float bal = 0.5f * Bf;               // PROP * batch
        float tot = 0.f;
        for (int c = 0; c < C_N; ++c) {
            const float cntp = acc[c * 5 + 0];
            const float sall = acc[c * 5 + 1];
            const float sp   = acc[c * 5 + 2];
            const float spe  = acc[c * 5 + 3];
            const float sne  = acc[c * 5 + 4];
            const float sn   = sall - sp;
            const bool posmaj = (cntp >= bal);     // pos_gt; else neg_gt
            const float nmaj = posmaj ? cntp : (Bf - cntp);
            const float nmin = Bf - nmaj;
            const float smaj = posmaj ? (sp - spe) : (sn - sne);
            const float smin = posmaj ? sn : sp;
            const float wmaj = bal / fmaxf(nmaj, 1.f);
            const float wmin = (nmin > 0.f) ? ((Bf - bal) / fmaxf(nmin, 1.f)) : 1.f;
            tot += smaj * wmaj + smin * wmin;
        }
        out[0] = tot / (Bf * (float)C_N);
    }
}

extern "C" void kernel_launch(void* const* d_in, const int* in_sizes, int n_in,
                              void* d_out, int out_size, void* d_ws, size_t ws_size,
                              hipStream_t stream) {
    const float* pred = (const float*)d_in[0];
    const float* tgt  = (const float*)d_in[1];
    float* gacc = (float*)d_ws;                       // NREP*200 floats = 25.6 KB
    hipMemsetAsync(gacc, 0, NREP * C_N * 5 * sizeof(float), stream);
    bdl_accum<<<GRID, BLOCK, 0, stream>>>(pred, tgt, gacc);
    bdl_final<<<1, 256, 0, stream>>>(gacc, (float*)d_out);
}

// Round 13
// 72.347 us; speedup vs baseline: 2.2232x; 1.0987x over previous
//
#include <hip/hip_runtime.h>
#include <math.h>

#define B_N 524288
#define C_N 40
constexpr int BLOCK  = 320;   // 5 waves; W = 320*4 = 1280 floats = 32 rows of C=40
constexpr int VEC    = 4;
constexpr int UNROLL = 8;     // 16 nt loads batched -> up to 8KB/wave in flight
constexpr int GRID   = 1024;  // tile=10240; 1024*10240*2 == B_N*C_N exactly (2 iters)
constexpr int NREP   = 32;    // accumulator replicas to spread atomic contention

typedef float f32x4 __attribute__((ext_vector_type(4)));

// Nontemporal streaming load (bypass L1 allocation) — R9's proven win.
__device__ __forceinline__ f32x4 ldnt(const float* p) {
    return __builtin_nontemporal_load(reinterpret_cast<const f32x4*>(p));
}

// R9 champion with the load batch doubled (the one lever that has tracked
// perf all session: bytes-in-flight per wave). launch_bounds(320,5) caps
// VGPR at ~102 so the 16-load batch (64 VGPR) + 20 accumulators fits
// without spill while keeping 4 blocks/CU resident.
__global__ __launch_bounds__(BLOCK, 5) void bdl_accum(
    const float* __restrict__ pred, const float* __restrict__ tgt,
    float* __restrict__ gacc)
{
    constexpr float  LN9    = 2.1972245773362196f;
    constexpr int    W      = BLOCK * VEC;                   // 1280 (== 0 mod 40)
    constexpr size_t TILE   = (size_t)W * UNROLL;            // 10240
    constexpr size_t STRIDE = (size_t)GRID * TILE;
    constexpr size_t TOTAL  = (size_t)B_N * C_N;

    float cntp[VEC] = {0.f,0.f,0.f,0.f};
    float sall[VEC] = {0.f,0.f,0.f,0.f};
    float spos[VEC] = {0.f,0.f,0.f,0.f};
    float spe[VEC]  = {0.f,0.f,0.f,0.f};
    float sne[VEC]  = {0.f,0.f,0.f,0.f};

    const int tid = threadIdx.x;

    for (size_t base = (size_t)blockIdx.x * TILE + (size_t)tid * VEC;
         base < TOTAL; base += STRIDE) {
        f32x4 p[UNROLL], t[UNROLL];
        #pragma unroll
        for (int u = 0; u < UNROLL; ++u) {
            p[u] = ldnt(pred + base + (size_t)u * W);
            t[u] = ldnt(tgt  + base + (size_t)u * W);
        }
        #pragma unroll
        for (int u = 0; u < UNROLL; ++u) {
            #pragma unroll
            for (int j = 0; j < VEC; ++j) {
                const float x  = p[u][j];
                const float tv = t[u][j];
                const float e  = __expf(-fabsf(x));
                const float sp_ = __logf(1.f + e);            // softplus(-|x|)
                const float bce = sp_ + fmaxf(x, 0.f) - x * tv;
                const float bpos = (x >  LN9) ? bce : 0.f;    // easy positive
                const float bneg = (x < -LN9) ? bce : 0.f;    // easy negative
                cntp[j] += tv;
                sall[j] += bce;
                spos[j]  = fmaf(tv, bce,   spos[j]);
                spe[j]   = fmaf(tv, bpos,  spe[j]);           // t * easy-pos
                sne[j]   = fmaf(-tv, bneg, sne[j] + bneg);    // (1-t) * easy-neg
            }
        }
    }

    __shared__ float lacc[C_N * 5];
    if (tid < C_N * 5) lacc[tid] = 0.f;
    __syncthreads();
    const int c0 = (tid * VEC) % C_N;          // constant classes per thread
    #pragma unroll
    for (int j = 0; j < VEC; ++j) {
        float* a = &lacc[(c0 + j) * 5];
        atomicAdd(a + 0, cntp[j]);
        atomicAdd(a + 1, sall[j]);
        atomicAdd(a + 2, spos[j]);
        atomicAdd(a + 3, spe[j]);
        atomicAdd(a + 4, sne[j]);
    }
    __syncthreads();
    if (tid < C_N * 5)
        atomicAdd(&gacc[(blockIdx.x % NREP) * (C_N * 5) + tid], lacc[tid]);
}

__global__ void bdl_final(const float* __restrict__ gacc, float* __restrict__ out)
{
    __shared__ float acc[C_N * 5];
    const int tid = threadIdx.x;
    if (tid < C_N * 5) {
        float s = 0.f;
        #pragma unroll
        for (int r = 0; r < NREP; ++r) s += gacc[r * (C_N * 5) + tid];
        acc[tid] = s;
    }
    __syncthreads();
    if (tid == 0) {
        const float Bf  = (float)B_N;
        const float bal = 0.5f * Bf;               // PROP * batch
        float tot = 0.f;
        for (int c = 0; c < C_N; ++c) {
            const float cntp = acc[c * 5 + 0];
            const float sall = acc[c * 5 + 1];
            const float sp   = acc[c * 5 + 2];
            const float spe  = acc[c * 5 + 3];
            const float sne  = acc[c * 5 + 4];
            const float sn   = sall - sp;
            const bool posmaj = (cntp >= bal);     // pos_gt; else neg_gt
            const float nmaj = posmaj ? cntp : (Bf - cntp);
            const float nmin = Bf - nmaj;
            const float smaj = posmaj ? (sp - spe) : (sn - sne);
            const float smin = posmaj ? sn : sp;
            const float wmaj = bal / fmaxf(nmaj, 1.f);
            const float wmin = (nmin > 0.f) ? ((Bf - bal) / fmaxf(nmin, 1.f)) : 1.f;
            tot += smaj * wmaj + smin * wmin;
        }
        out[0] = tot / (Bf * (float)C_N);
    }
}

extern "C" void kernel_launch(void* const* d_in, const int* in_sizes, int n_in,
                              void* d_out, int out_size, void* d_ws, size_t ws_size,
                              hipStream_t stream) {
    const float* pred = (const float*)d_in[0];
    const float* tgt  = (const float*)d_in[1];
    float* gacc = (float*)d_ws;                       // NREP*200 floats = 25.6 KB
    hipMemsetAsync(gacc, 0, NREP * C_N * 5 * sizeof(float), stream);
    bdl_accum<<<GRID, BLOCK, 0, stream>>>(pred, tgt, gacc);
    bdl_final<<<1, 256, 0, stream>>>(gacc, (float*)d_out);
}